// Round 8
// baseline (204.159 us; speedup 1.0000x reference)
//
#include <hip/hip_runtime.h>

#define HID 1024
#define SEQ 2048
#define NB 2
#define NH 16
#define HD 64

// 0.125 * log2(e)  (1/sqrt(64) folded into log2 domain)
#define C1 0.1803368801111204f
// gamma * log2(e)
#define C2 0.7213475204444817f

typedef __attribute__((ext_vector_type(8))) short bf16x8;
typedef __attribute__((ext_vector_type(8))) unsigned short u16x8;
typedef __attribute__((ext_vector_type(4))) float f32x4;

__device__ __forceinline__ unsigned short f2bf(float f) {
  unsigned u = __builtin_bit_cast(unsigned, f);
  u += 0x7fffu + ((u >> 16) & 1u);
  return (unsigned short)(u >> 16);
}
__device__ __forceinline__ float bf2f(unsigned short u) {
  return __builtin_bit_cast(float, ((unsigned)u) << 16);
}

#define GLOAD16(gsrc, ldst)                                                     \
  __builtin_amdgcn_global_load_lds(                                             \
      (const __attribute__((address_space(1))) void*)(gsrc),                    \
      (__attribute__((address_space(3))) void*)(ldst), 16, 0, 0)

// ---- convert the 4 weight matrices f32 -> bf16 into one contiguous buffer ----
__global__ __launch_bounds__(256) void convert_w_kernel(
    const float* __restrict__ Wq, const float* __restrict__ Wk,
    const float* __restrict__ Wv, const float* __restrict__ Wo,
    unsigned short* __restrict__ Wb) {
  int i = blockIdx.x * 256 + threadIdx.x;
  const int per = (HID * HID) / 8;
  int m = i / per;
  const float* sp = (m == 0) ? Wq : (m == 1) ? Wk : (m == 2) ? Wv : Wo;
  int j = (i - m * per) * 8;
  const float4* p = reinterpret_cast<const float4*>(sp + j);
  float4 a = p[0], b = p[1];
  u16x8 o;
  o[0] = f2bf(a.x); o[1] = f2bf(a.y); o[2] = f2bf(a.z); o[3] = f2bf(a.w);
  o[4] = f2bf(b.x); o[5] = f2bf(b.y); o[6] = f2bf(b.z); o[7] = f2bf(b.w);
  *reinterpret_cast<u16x8*>(Wb + (size_t)i * 8) = o;
}

// ---- per-row L2 norm of x; emit x (bf16) and normalized x (bf16) ----
__global__ __launch_bounds__(256) void rownorm_kernel(
    const float* __restrict__ x, unsigned short* __restrict__ xb,
    unsigned short* __restrict__ nxb) {
  int row = blockIdx.x, tid = threadIdx.x;
  const float4 v = reinterpret_cast<const float4*>(x + (size_t)row * HID)[tid];
  float ss = v.x * v.x + v.y * v.y + v.z * v.z + v.w * v.w;
#pragma unroll
  for (int off = 32; off; off >>= 1) ss += __shfl_xor(ss, off, 64);
  __shared__ float wsum[4];
  if ((tid & 63) == 0) wsum[tid >> 6] = ss;
  __syncthreads();
  float tot = wsum[0] + wsum[1] + wsum[2] + wsum[3];
  float inv = 1.0f / fmaxf(sqrtf(tot), 1e-12f);
  ushort4 a, b;
  a.x = f2bf(v.x); a.y = f2bf(v.y); a.z = f2bf(v.z); a.w = f2bf(v.w);
  b.x = f2bf(v.x * inv); b.y = f2bf(v.y * inv);
  b.z = f2bf(v.z * inv); b.w = f2bf(v.w * inv);
  reinterpret_cast<ushort4*>(xb  + (size_t)row * HID)[tid] = a;
  reinterpret_cast<ushort4*>(nxb + (size_t)row * HID)[tid] = b;
}

// ---- generic NT bf16 GEMM: C = A[M,K] * B[N,K]^T, f32 accum ----
// Staging via global_load_lds width=16 into unpadded [128][32] tiles.
// MODE 0: bf16 out, col bias (b0 / b1 split at 1024)
// MODE 1: bf16 out = -C2*acc + (mask ? -1e30 : 0)
// MODE 2: f32 out + col bias
// MODE 3: bf16 out + ROW bias (for V^T = Wv x^T)
template <int MODE>
__global__ __launch_bounds__(256) void gemm_nt(
    const unsigned short* __restrict__ A, long strideA,
    const unsigned short* __restrict__ B, long strideB,
    void* __restrict__ Cv, long strideC, int ldc,
    int M, int N, int K,
    const float* __restrict__ b0, const float* __restrict__ b1,
    const float* __restrict__ b2, const unsigned char* __restrict__ mask) {
  __shared__ __align__(16) unsigned short As[128 * 32];
  __shared__ __align__(16) unsigned short Bs[128 * 32];
  int tid = threadIdx.x, lane = tid & 63, wid = tid >> 6;
  int g = lane >> 4, lr = lane & 15;
  int wr = wid >> 1, wc = wid & 1;
  int m0 = blockIdx.y * 128, n0 = blockIdx.x * 128;
  const unsigned short* Ab = A + (size_t)blockIdx.z * strideA
      + (size_t)(m0 + wid * 32 + (lane >> 2)) * K + (lane & 3) * 8;
  const unsigned short* Bb = B + (size_t)blockIdx.z * strideB
      + (size_t)(n0 + wid * 32 + (lane >> 2)) * K + (lane & 3) * 8;
  unsigned short* la = As + wid * 1024;
  unsigned short* lb = Bs + wid * 1024;
  f32x4 acc[4][4] = {};
  for (int k0 = 0; k0 < K; k0 += 32) {
    GLOAD16(Ab + k0, la);
    GLOAD16(Ab + 16 * K + k0, la + 512);
    GLOAD16(Bb + k0, lb);
    GLOAD16(Bb + 16 * K + k0, lb + 512);
    __syncthreads();
    bf16x8 af[4], bfr[4];
#pragma unroll
    for (int i = 0; i < 4; i++) {
      af[i]  = *reinterpret_cast<const bf16x8*>(&As[(wr * 64 + i * 16 + lr) * 32 + g * 8]);
      bfr[i] = *reinterpret_cast<const bf16x8*>(&Bs[(wc * 64 + i * 16 + lr) * 32 + g * 8]);
    }
#pragma unroll
    for (int i = 0; i < 4; i++)
#pragma unroll
      for (int j = 0; j < 4; j++)
        acc[i][j] = __builtin_amdgcn_mfma_f32_16x16x32_bf16(af[i], bfr[j], acc[i][j], 0, 0, 0);
    __syncthreads();
  }
#pragma unroll
  for (int i = 0; i < 4; i++)
#pragma unroll
    for (int j = 0; j < 4; j++) {
      int col = n0 + wc * 64 + j * 16 + lr;
#pragma unroll
      for (int r = 0; r < 4; r++) {
        int row = m0 + wr * 64 + i * 16 + 4 * g + r;
        float v = acc[i][j][r];
        if (MODE == 0) {
          const float* bp = (col < 1024) ? b0 : b1;
          v += bp[col & 1023];
          ((unsigned short*)Cv)[(size_t)blockIdx.z * strideC + (size_t)row * ldc + col] = f2bf(v);
        } else if (MODE == 1) {
          float t = -C2 * v + (mask[(size_t)row * N + col] ? -1e30f : 0.0f);
          ((unsigned short*)Cv)[(size_t)blockIdx.z * strideC + (size_t)row * ldc + col] = f2bf(t);
        } else if (MODE == 2) {
          v += b0[col];
          ((float*)Cv)[(size_t)blockIdx.z * strideC + (size_t)row * ldc + col] = v;
        } else {
          v += b0[row];
          ((unsigned short*)Cv)[(size_t)blockIdx.z * strideC + (size_t)row * ldc + col] = f2bf(v);
        }
      }
    }
}

// ---- flash attention v7: both K and V^T staged via global_load_lds ----
// K kappa-permuted (in-register P, see v6); V^T precomputed by MODE-3 GEMM so
// flash does no transpose work. No-max softmax in log2 domain.
__global__ __launch_bounds__(256, 4) void flash_kernel(
    const unsigned short* __restrict__ QK,   // [4096][2048] bf16 (Q|K)
    const unsigned short* __restrict__ VT,   // [1024][4096] bf16 (d, b*2048+s)
    const unsigned short* __restrict__ D2,   // [2][2048][2048] bf16 log2-bias
    unsigned short* __restrict__ ctxb) {     // [4096][1024] bf16
  int h = blockIdx.x, qt = blockIdx.y, b = blockIdx.z;
  int tid = threadIdx.x, wid = tid >> 6, lane = tid & 63;
  int g = lane >> 4, lr = lane & 15;
  __shared__ __align__(16) unsigned short Ks[2][64 * 64];  // 16 KiB
  __shared__ __align__(16) unsigned short Vt[2][64 * 64];  // 16 KiB
  const size_t ld = 2 * HID;
  const size_t bS = (size_t)b * SEQ;
  const int qbase = qt * 64 + wid * 16;

  // Q fragment (B operand): rows qbase+lr; lane group g holds d=8g+j (+32)
  const unsigned short* qp = QK + (bS + qbase + lr) * ld + h * HD + g * 8;
  bf16x8 qf0 = *reinterpret_cast<const bf16x8*>(qp);
  bf16x8 qf1 = *reinterpret_cast<const bf16x8*>(qp + 32);

  // K staging: LDS position row p = wid*16 + (lane>>3) (+8 for gK1) holds
  // key kappa(p); chunk pre-swizzle c' = (lane&7) ^ (lane>>3).
  const int p0 = wid * 16 + (lane >> 3);
  const int key0 = ((p0 >> 5) & 1) * 32 + (((p0 >> 2) & 3) << 3)
                 + ((p0 >> 4) & 1) * 4 + (p0 & 3);  // kappa(p0); kappa(p0+8)=key0+16
  const unsigned short* gK0 = QK + (bS + key0) * ld + HID + h * HD
                              + (((lane & 7) ^ (lane >> 3)) << 3);
  const unsigned short* gK1 = gK0 + 16 * ld;  // kappa(p0+8) = key0 + 16

  // V^T staging: identity rows d = wid*16 + (lane>>3) (+8), same chunk swizzle
  const unsigned short* gV0 = VT + (size_t)(h * HD + wid * 16 + (lane >> 3)) * (2 * SEQ)
                              + bS + (((lane & 7) ^ (lane >> 3)) << 3);
  const unsigned short* gV1 = gV0 + (size_t)8 * (2 * SEQ);

  // log2-domain bias row (lane owns q = qbase + lr); kappa key offsets per kc
  const unsigned short* bD = D2 + (size_t)b * SEQ * SEQ
                             + (size_t)(qbase + lr) * SEQ + 8 * g;
  // kc offsets: 32*(kc>>1) + 4*(kc&1) = {0, 4, 32, 36}

  // prologue: stage tile 0 into buffer 0; preload bias for tile 0
  GLOAD16(gK0, &Ks[0][wid * 1024]);
  GLOAD16(gK1, &Ks[0][wid * 1024 + 512]);
  GLOAD16(gV0, &Vt[0][wid * 1024]);
  GLOAD16(gV1, &Vt[0][wid * 1024 + 512]);
  ushort4 bvc[4];
  bvc[0] = *reinterpret_cast<const ushort4*>(bD + 0);
  bvc[1] = *reinterpret_cast<const ushort4*>(bD + 4);
  bvc[2] = *reinterpret_cast<const ushort4*>(bD + 32);
  bvc[3] = *reinterpret_cast<const ushort4*>(bD + 36);
  __syncthreads();

  f32x4 acc[4] = {};
  f32x4 rsacc = {};
  const int kb0 = lr * 64 + ((g ^ (lr & 7)) << 3);
  bf16x8 ones;
#pragma unroll
  for (int i = 0; i < 8; i++) ones[i] = 0x3F80;  // bf16 1.0

  for (int kt = 0; kt < 32; ++kt) {
    const int cb = kt & 1;
    const unsigned short* ks = &Ks[cb][0];
    const unsigned short* vt = &Vt[cb][0];
    ushort4 bvn[4];
    if (kt < 31) {  // prefetch next tile: K,V -> LDS (DMA), bias -> regs
      GLOAD16(gK0 + (size_t)(kt + 1) * 64 * ld, &Ks[cb ^ 1][wid * 1024]);
      GLOAD16(gK1 + (size_t)(kt + 1) * 64 * ld, &Ks[cb ^ 1][wid * 1024 + 512]);
      GLOAD16(gV0 + (kt + 1) * 64, &Vt[cb ^ 1][wid * 1024]);
      GLOAD16(gV1 + (kt + 1) * 64, &Vt[cb ^ 1][wid * 1024 + 512]);
      const unsigned short* bn = bD + (kt + 1) * 64;
      bvn[0] = *reinterpret_cast<const ushort4*>(bn + 0);
      bvn[1] = *reinterpret_cast<const ushort4*>(bn + 4);
      bvn[2] = *reinterpret_cast<const ushort4*>(bn + 32);
      bvn[3] = *reinterpret_cast<const ushort4*>(bn + 36);
    }

    // S^T = K Q^T  (A = K frag from kappa-permuted LDS, B = Q frag)
    f32x4 s[4];
    __builtin_amdgcn_s_setprio(1);
#pragma unroll
    for (int kc = 0; kc < 4; kc++) {
      bf16x8 kf0 = *reinterpret_cast<const bf16x8*>(ks + kc * 1024 + kb0);
      bf16x8 kf1 = *reinterpret_cast<const bf16x8*>(ks + kc * 1024 + (kb0 ^ 32));
      f32x4 z = {};
      z = __builtin_amdgcn_mfma_f32_16x16x32_bf16(kf0, qf0, z, 0, 0, 0);
      s[kc] = __builtin_amdgcn_mfma_f32_16x16x32_bf16(kf1, qf1, z, 0, 0, 0);
    }
    __builtin_amdgcn_s_setprio(0);

    // P = exp2(0.18*qk + bias) directly; pack in-register into PV A-frags
    bf16x8 pa[2];
#pragma unroll
    for (int c2 = 0; c2 < 2; c2++) {
      float p0f = exp2f(fmaf(s[2 * c2][0], C1, bf2f(bvc[2 * c2].x)));
      float p1f = exp2f(fmaf(s[2 * c2][1], C1, bf2f(bvc[2 * c2].y)));
      float p2f = exp2f(fmaf(s[2 * c2][2], C1, bf2f(bvc[2 * c2].z)));
      float p3f = exp2f(fmaf(s[2 * c2][3], C1, bf2f(bvc[2 * c2].w)));
      float p4f = exp2f(fmaf(s[2 * c2 + 1][0], C1, bf2f(bvc[2 * c2 + 1].x)));
      float p5f = exp2f(fmaf(s[2 * c2 + 1][1], C1, bf2f(bvc[2 * c2 + 1].y)));
      float p6f = exp2f(fmaf(s[2 * c2 + 1][2], C1, bf2f(bvc[2 * c2 + 1].z)));
      float p7f = exp2f(fmaf(s[2 * c2 + 1][3], C1, bf2f(bvc[2 * c2 + 1].w)));
      uint4 W;
      W.x = __builtin_amdgcn_perm(__builtin_bit_cast(unsigned, p1f),
                                  __builtin_bit_cast(unsigned, p0f), 0x07060302u);
      W.y = __builtin_amdgcn_perm(__builtin_bit_cast(unsigned, p3f),
                                  __builtin_bit_cast(unsigned, p2f), 0x07060302u);
      W.z = __builtin_amdgcn_perm(__builtin_bit_cast(unsigned, p5f),
                                  __builtin_bit_cast(unsigned, p4f), 0x07060302u);
      W.w = __builtin_amdgcn_perm(__builtin_bit_cast(unsigned, p7f),
                                  __builtin_bit_cast(unsigned, p6f), 0x07060302u);
      pa[c2] = __builtin_bit_cast(bf16x8, W);
    }

    // ctx += P V ; l += P . ones   (P straight from registers)
    __builtin_amdgcn_s_setprio(1);
#pragma unroll
    for (int c2 = 0; c2 < 2; c2++) {
      rsacc = __builtin_amdgcn_mfma_f32_16x16x32_bf16(pa[c2], ones, rsacc, 0, 0, 0);
#pragma unroll
      for (int df = 0; df < 4; df++) {
        bf16x8 vf = *reinterpret_cast<const bf16x8*>(
            vt + (df * 16 + lr) * 64 + (((4 * c2 + g) ^ (lr & 7)) << 3));
        acc[df] = __builtin_amdgcn_mfma_f32_16x16x32_bf16(pa[c2], vf, acc[df], 0, 0, 0);
      }
    }
    __builtin_amdgcn_s_setprio(0);

    if (kt < 31) {
      bvc[0] = bvn[0]; bvc[1] = bvn[1]; bvc[2] = bvn[2]; bvc[3] = bvn[3];
    }
    __syncthreads();
  }
  // epilogue: normalize and store (stats already in acc row layout)
  float l0 = 1.0f / rsacc[0], l1 = 1.0f / rsacc[1];
  float l2 = 1.0f / rsacc[2], l3 = 1.0f / rsacc[3];
  unsigned short* op = ctxb + (bS + qbase + 4 * g) * HID + h * HD + lr;
#pragma unroll
  for (int df = 0; df < 4; df++) {
    op[0 * HID + df * 16] = f2bf(acc[df][0] * l0);
    op[1 * HID + df * 16] = f2bf(acc[df][1] * l1);
    op[2 * HID + df * 16] = f2bf(acc[df][2] * l2);
    op[3 * HID + df * 16] = f2bf(acc[df][3] * l3);
  }
}

extern "C" void kernel_launch(void* const* d_in, const int* in_sizes, int n_in,
                              void* d_out, int out_size, void* d_ws, size_t ws_size,
                              hipStream_t stream) {
  const float* x = (const float*)d_in[0];
  const unsigned char* mask = (const unsigned char*)d_in[1];
  const float* Wq = (const float*)d_in[2];
  const float* bq = (const float*)d_in[3];
  const float* Wk = (const float*)d_in[4];
  const float* bk = (const float*)d_in[5];
  const float* Wv = (const float*)d_in[6];
  const float* bv = (const float*)d_in[7];
  const float* Wo = (const float*)d_in[8];
  const float* bo = (const float*)d_in[9];
  float* out = (float*)d_out;

  char* ws = (char*)d_ws;
  const size_t MiB = 1024 * 1024;
  unsigned short* xb  = (unsigned short*)(ws + 0 * MiB);   // 8 MiB
  unsigned short* nxb = (unsigned short*)(ws + 8 * MiB);   // 8 MiB
  unsigned short* Wb  = (unsigned short*)(ws + 16 * MiB);  // 8 MiB
  unsigned short* QK  = (unsigned short*)(ws + 24 * MiB);  // 16 MiB [4096][2048]
  unsigned short* VT  = (unsigned short*)(ws + 40 * MiB);  // 8 MiB  [1024][4096]
  unsigned short* D2  = (unsigned short*)(ws + 48 * MiB);  // 16 MiB bf16 log2-bias
  unsigned short* ctx = (unsigned short*)(ws + 64 * MiB);  // 8 MiB

  convert_w_kernel<<<2048, 256, 0, stream>>>(Wq, Wk, Wv, Wo, Wb);
  rownorm_kernel<<<NB * SEQ, 256, 0, stream>>>(x, xb, nxb);
  // fused Q|K projection: [4096,1024] x [2048,1024]^T -> [4096,2048] bf16
  gemm_nt<0><<<dim3(16, 32, 1), 256, 0, stream>>>(
      xb, 0, Wb, 0, QK, 0, 2 * HID, NB * SEQ, 2 * HID, HID, bq, bk, nullptr, nullptr);
  // V^T projection: Wv[1024,1024] x xb[4096,1024]^T -> VT[1024][4096] bf16 (+row bias)
  gemm_nt<3><<<dim3(32, 8, 1), 256, 0, stream>>>(
      Wb + (size_t)2 * HID * HID, 0, xb, 0, VT, 0, 2 * SEQ, HID, NB * SEQ, HID,
      bv, nullptr, nullptr, nullptr);
  // diversity bias (log2 domain, bf16): D' = -gamma*log2e*sim + mask*(-1e30)
  gemm_nt<1><<<dim3(16, 16, 2), 256, 0, stream>>>(
      nxb, (long)SEQ * HID, nxb, (long)SEQ * HID, D2, (long)SEQ * SEQ, SEQ,
      SEQ, SEQ, HID, nullptr, nullptr, nullptr, mask);
  // flash attention over all heads
  flash_kernel<<<dim3(NH, SEQ / 64, NB), 256, 0, stream>>>(QK, VT, D2, ctx);
  // output projection
  gemm_nt<2><<<dim3(8, 32, 1), 256, 0, stream>>>(
      ctx, 0, Wb + (size_t)3 * HID * HID, 0, out, 0, HID, NB * SEQ, HID, HID,
      bo, nullptr, nullptr, nullptr);
}

// Round 9
// 196.278 us; speedup vs baseline: 1.0402x; 1.0402x over previous
//
#include <hip/hip_runtime.h>

#define HID 1024
#define SEQ 2048
#define NB 2
#define NH 16
#define HD 64

// 0.125 * log2(e)  (1/sqrt(64) folded into log2 domain)
#define C1 0.1803368801111204f
// gamma * log2(e)
#define C2 0.7213475204444817f

typedef __attribute__((ext_vector_type(8))) short bf16x8;
typedef __attribute__((ext_vector_type(8))) unsigned short u16x8;
typedef __attribute__((ext_vector_type(4))) float f32x4;

__device__ __forceinline__ unsigned short f2bf(float f) {
  unsigned u = __builtin_bit_cast(unsigned, f);
  u += 0x7fffu + ((u >> 16) & 1u);
  return (unsigned short)(u >> 16);
}
__device__ __forceinline__ float bf2f(unsigned short u) {
  return __builtin_bit_cast(float, ((unsigned)u) << 16);
}

#define GLOAD16(gsrc, ldst)                                                     \
  __builtin_amdgcn_global_load_lds(                                             \
      (const __attribute__((address_space(1))) void*)(gsrc),                    \
      (__attribute__((address_space(3))) void*)(ldst), 16, 0, 0)

// ---- prep: weights f32->bf16 (blocks 0..2047) + rownorm (blocks 2048..6143) ----
__global__ __launch_bounds__(256) void prep_kernel(
    const float* __restrict__ x,
    const float* __restrict__ Wq, const float* __restrict__ Wk,
    const float* __restrict__ Wv, const float* __restrict__ Wo,
    unsigned short* __restrict__ Wb,
    unsigned short* __restrict__ xb, unsigned short* __restrict__ nxb) {
  int tid = threadIdx.x;
  if (blockIdx.x < 2048) {
    int i = blockIdx.x * 256 + tid;
    const int per = (HID * HID) / 8;
    int m = i / per;
    const float* sp = (m == 0) ? Wq : (m == 1) ? Wk : (m == 2) ? Wv : Wo;
    int j = (i - m * per) * 8;
    const float4* p = reinterpret_cast<const float4*>(sp + j);
    float4 a = p[0], b = p[1];
    u16x8 o;
    o[0] = f2bf(a.x); o[1] = f2bf(a.y); o[2] = f2bf(a.z); o[3] = f2bf(a.w);
    o[4] = f2bf(b.x); o[5] = f2bf(b.y); o[6] = f2bf(b.z); o[7] = f2bf(b.w);
    *reinterpret_cast<u16x8*>(Wb + (size_t)i * 8) = o;
  } else {
    int row = blockIdx.x - 2048;
    const float4 v = reinterpret_cast<const float4*>(x + (size_t)row * HID)[tid];
    float ss = v.x * v.x + v.y * v.y + v.z * v.z + v.w * v.w;
#pragma unroll
    for (int off = 32; off; off >>= 1) ss += __shfl_xor(ss, off, 64);
    __shared__ float wsum[4];
    if ((tid & 63) == 0) wsum[tid >> 6] = ss;
    __syncthreads();
    float tot = wsum[0] + wsum[1] + wsum[2] + wsum[3];
    float inv = 1.0f / fmaxf(sqrtf(tot), 1e-12f);
    ushort4 a, b;
    a.x = f2bf(v.x); a.y = f2bf(v.y); a.z = f2bf(v.z); a.w = f2bf(v.w);
    b.x = f2bf(v.x * inv); b.y = f2bf(v.y * inv);
    b.z = f2bf(v.z * inv); b.w = f2bf(v.w * inv);
    reinterpret_cast<ushort4*>(xb  + (size_t)row * HID)[tid] = a;
    reinterpret_cast<ushort4*>(nxb + (size_t)row * HID)[tid] = b;
  }
}

// ---- mega GEMM: QK-proj (512 blks) | VT-proj (256) | sym-sim (2x136) ----
// All share K=1024 NT inner loop (global_load_lds staging, [128][32] tiles);
// per-block scalar decode picks operands and epilogue.
__global__ __launch_bounds__(256) void mega_gemm(
    const unsigned short* __restrict__ xb, const unsigned short* __restrict__ nxb,
    const unsigned short* __restrict__ Wb,
    unsigned short* __restrict__ QK, unsigned short* __restrict__ VT,
    unsigned short* __restrict__ D2,
    const float* __restrict__ bq, const float* __restrict__ bk,
    const float* __restrict__ bv, const unsigned char* __restrict__ mask) {
  const int K = HID;
  int bid = blockIdx.x;
  int mode, m0, n0;
  const unsigned short *A, *B;
  size_t zoff = 0;
  if (bid < 512) {                      // QK projection: [4096]x[2048]
    mode = 0; m0 = (bid >> 4) * 128; n0 = (bid & 15) * 128;
    A = xb; B = Wb;
  } else if (bid < 768) {               // VT projection: [1024]x[4096]
    mode = 3; int t = bid - 512; m0 = (t >> 5) * 128; n0 = (t & 31) * 128;
    A = Wb + (size_t)2 * HID * HID; B = xb;
  } else {                              // symmetric sim, upper triangle blocks
    mode = 1; int t = bid - 768; int z = 0;
    if (t >= 136) { z = 1; t -= 136; }
    int a = (int)((sqrtf(8.0f * t + 1.0f) - 1.0f) * 0.5f);
    while (a * (a + 1) / 2 > t) a--;
    while ((a + 1) * (a + 2) / 2 <= t) a++;
    int bI = t - a * (a + 1) / 2;       // row block (q), bI <= bJ
    m0 = bI * 128; n0 = a * 128;
    A = nxb + (size_t)z * SEQ * HID; B = A;
    zoff = (size_t)z * SEQ * SEQ;
  }

  __shared__ __align__(16) unsigned short As[128 * 32];
  __shared__ __align__(16) unsigned short Bs[128 * 32];
  int tid = threadIdx.x, lane = tid & 63, wid = tid >> 6;
  int g = lane >> 4, lr = lane & 15;
  int wr = wid >> 1, wc = wid & 1;
  const unsigned short* Ab = A + (size_t)(m0 + wid * 32 + (lane >> 2)) * K + (lane & 3) * 8;
  const unsigned short* Bb = B + (size_t)(n0 + wid * 32 + (lane >> 2)) * K + (lane & 3) * 8;
  unsigned short* la = As + wid * 1024;
  unsigned short* lb = Bs + wid * 1024;
  f32x4 acc[4][4] = {};
  for (int k0 = 0; k0 < K; k0 += 32) {
    GLOAD16(Ab + k0, la);
    GLOAD16(Ab + 16 * K + k0, la + 512);
    GLOAD16(Bb + k0, lb);
    GLOAD16(Bb + 16 * K + k0, lb + 512);
    __syncthreads();
    bf16x8 af[4], bfr[4];
#pragma unroll
    for (int i = 0; i < 4; i++) {
      af[i]  = *reinterpret_cast<const bf16x8*>(&As[(wr * 64 + i * 16 + lr) * 32 + g * 8]);
      bfr[i] = *reinterpret_cast<const bf16x8*>(&Bs[(wc * 64 + i * 16 + lr) * 32 + g * 8]);
    }
#pragma unroll
    for (int i = 0; i < 4; i++)
#pragma unroll
      for (int j = 0; j < 4; j++)
        acc[i][j] = __builtin_amdgcn_mfma_f32_16x16x32_bf16(af[i], bfr[j], acc[i][j], 0, 0, 0);
    __syncthreads();
  }
#pragma unroll
  for (int i = 0; i < 4; i++)
#pragma unroll
    for (int j = 0; j < 4; j++) {
      int col = n0 + wc * 64 + j * 16 + lr;
#pragma unroll
      for (int r = 0; r < 4; r++) {
        int row = m0 + wr * 64 + i * 16 + 4 * g + r;
        float v = acc[i][j][r];
        if (mode == 0) {
          const float* bp = (col < 1024) ? bq : bk;
          QK[(size_t)row * 2048 + col] = f2bf(v + bp[col & 1023]);
        } else if (mode == 3) {
          VT[(size_t)row * 4096 + col] = f2bf(v + bv[row]);
        } else {
          float t1 = -C2 * v + (mask[(size_t)row * SEQ + col] ? -1e30f : 0.0f);
          D2[zoff + (size_t)row * SEQ + col] = f2bf(t1);
          if (m0 != n0) {
            float t2 = -C2 * v + (mask[(size_t)col * SEQ + row] ? -1e30f : 0.0f);
            D2[zoff + (size_t)col * SEQ + row] = f2bf(t2);
          }
        }
      }
    }
}

// ---- out projection: C = ctx[4096,1024] x Wo[1024,1024]^T + bo, f32 out ----
__global__ __launch_bounds__(256) void gemm_out(
    const unsigned short* __restrict__ A, const unsigned short* __restrict__ B,
    float* __restrict__ C, const float* __restrict__ b0) {
  const int K = HID;
  __shared__ __align__(16) unsigned short As[128 * 32];
  __shared__ __align__(16) unsigned short Bs[128 * 32];
  int tid = threadIdx.x, lane = tid & 63, wid = tid >> 6;
  int g = lane >> 4, lr = lane & 15;
  int wr = wid >> 1, wc = wid & 1;
  int m0 = blockIdx.y * 128, n0 = blockIdx.x * 128;
  const unsigned short* Ab = A + (size_t)(m0 + wid * 32 + (lane >> 2)) * K + (lane & 3) * 8;
  const unsigned short* Bb = B + (size_t)(n0 + wid * 32 + (lane >> 2)) * K + (lane & 3) * 8;
  unsigned short* la = As + wid * 1024;
  unsigned short* lb = Bs + wid * 1024;
  f32x4 acc[4][4] = {};
  for (int k0 = 0; k0 < K; k0 += 32) {
    GLOAD16(Ab + k0, la);
    GLOAD16(Ab + 16 * K + k0, la + 512);
    GLOAD16(Bb + k0, lb);
    GLOAD16(Bb + 16 * K + k0, lb + 512);
    __syncthreads();
    bf16x8 af[4], bfr[4];
#pragma unroll
    for (int i = 0; i < 4; i++) {
      af[i]  = *reinterpret_cast<const bf16x8*>(&As[(wr * 64 + i * 16 + lr) * 32 + g * 8]);
      bfr[i] = *reinterpret_cast<const bf16x8*>(&Bs[(wc * 64 + i * 16 + lr) * 32 + g * 8]);
    }
#pragma unroll
    for (int i = 0; i < 4; i++)
#pragma unroll
      for (int j = 0; j < 4; j++)
        acc[i][j] = __builtin_amdgcn_mfma_f32_16x16x32_bf16(af[i], bfr[j], acc[i][j], 0, 0, 0);
    __syncthreads();
  }
#pragma unroll
  for (int i = 0; i < 4; i++)
#pragma unroll
    for (int j = 0; j < 4; j++) {
      int col = n0 + wc * 64 + j * 16 + lr;
#pragma unroll
      for (int r = 0; r < 4; r++) {
        int row = m0 + wr * 64 + i * 16 + 4 * g + r;
        C[(size_t)row * HID + col] = acc[i][j][r] + b0[col];
      }
    }
}

// ---- flash attention v7: both K and V^T staged via global_load_lds ----
// K kappa-permuted (in-register P); V^T precomputed by mega_gemm; no-max
// softmax in log2 domain. Unchanged from round 8.
__global__ __launch_bounds__(256, 4) void flash_kernel(
    const unsigned short* __restrict__ QK,   // [4096][2048] bf16 (Q|K)
    const unsigned short* __restrict__ VT,   // [1024][4096] bf16 (d, b*2048+s)
    const unsigned short* __restrict__ D2,   // [2][2048][2048] bf16 log2-bias
    unsigned short* __restrict__ ctxb) {     // [4096][1024] bf16
  int h = blockIdx.x, qt = blockIdx.y, b = blockIdx.z;
  int tid = threadIdx.x, wid = tid >> 6, lane = tid & 63;
  int g = lane >> 4, lr = lane & 15;
  __shared__ __align__(16) unsigned short Ks[2][64 * 64];  // 16 KiB
  __shared__ __align__(16) unsigned short Vt[2][64 * 64];  // 16 KiB
  const size_t ld = 2 * HID;
  const size_t bS = (size_t)b * SEQ;
  const int qbase = qt * 64 + wid * 16;

  const unsigned short* qp = QK + (bS + qbase + lr) * ld + h * HD + g * 8;
  bf16x8 qf0 = *reinterpret_cast<const bf16x8*>(qp);
  bf16x8 qf1 = *reinterpret_cast<const bf16x8*>(qp + 32);

  const int p0 = wid * 16 + (lane >> 3);
  const int key0 = ((p0 >> 5) & 1) * 32 + (((p0 >> 2) & 3) << 3)
                 + ((p0 >> 4) & 1) * 4 + (p0 & 3);
  const unsigned short* gK0 = QK + (bS + key0) * ld + HID + h * HD
                              + (((lane & 7) ^ (lane >> 3)) << 3);
  const unsigned short* gK1 = gK0 + 16 * ld;

  const unsigned short* gV0 = VT + (size_t)(h * HD + wid * 16 + (lane >> 3)) * (2 * SEQ)
                              + bS + (((lane & 7) ^ (lane >> 3)) << 3);
  const unsigned short* gV1 = gV0 + (size_t)8 * (2 * SEQ);

  const unsigned short* bD = D2 + (size_t)b * SEQ * SEQ
                             + (size_t)(qbase + lr) * SEQ + 8 * g;

  GLOAD16(gK0, &Ks[0][wid * 1024]);
  GLOAD16(gK1, &Ks[0][wid * 1024 + 512]);
  GLOAD16(gV0, &Vt[0][wid * 1024]);
  GLOAD16(gV1, &Vt[0][wid * 1024 + 512]);
  ushort4 bvc[4];
  bvc[0] = *reinterpret_cast<const ushort4*>(bD + 0);
  bvc[1] = *reinterpret_cast<const ushort4*>(bD + 4);
  bvc[2] = *reinterpret_cast<const ushort4*>(bD + 32);
  bvc[3] = *reinterpret_cast<const ushort4*>(bD + 36);
  __syncthreads();

  f32x4 acc[4] = {};
  f32x4 rsacc = {};
  const int kb0 = lr * 64 + ((g ^ (lr & 7)) << 3);
  bf16x8 ones;
#pragma unroll
  for (int i = 0; i < 8; i++) ones[i] = 0x3F80;  // bf16 1.0

  for (int kt = 0; kt < 32; ++kt) {
    const int cb = kt & 1;
    const unsigned short* ks = &Ks[cb][0];
    const unsigned short* vt = &Vt[cb][0];
    ushort4 bvn[4];
    if (kt < 31) {
      GLOAD16(gK0 + (size_t)(kt + 1) * 64 * ld, &Ks[cb ^ 1][wid * 1024]);
      GLOAD16(gK1 + (size_t)(kt + 1) * 64 * ld, &Ks[cb ^ 1][wid * 1024 + 512]);
      GLOAD16(gV0 + (kt + 1) * 64, &Vt[cb ^ 1][wid * 1024]);
      GLOAD16(gV1 + (kt + 1) * 64, &Vt[cb ^ 1][wid * 1024 + 512]);
      const unsigned short* bn = bD + (kt + 1) * 64;
      bvn[0] = *reinterpret_cast<const ushort4*>(bn + 0);
      bvn[1] = *reinterpret_cast<const ushort4*>(bn + 4);
      bvn[2] = *reinterpret_cast<const ushort4*>(bn + 32);
      bvn[3] = *reinterpret_cast<const ushort4*>(bn + 36);
    }

    f32x4 s[4];
    __builtin_amdgcn_s_setprio(1);
#pragma unroll
    for (int kc = 0; kc < 4; kc++) {
      bf16x8 kf0 = *reinterpret_cast<const bf16x8*>(ks + kc * 1024 + kb0);
      bf16x8 kf1 = *reinterpret_cast<const bf16x8*>(ks + kc * 1024 + (kb0 ^ 32));
      f32x4 z = {};
      z = __builtin_amdgcn_mfma_f32_16x16x32_bf16(kf0, qf0, z, 0, 0, 0);
      s[kc] = __builtin_amdgcn_mfma_f32_16x16x32_bf16(kf1, qf1, z, 0, 0, 0);
    }
    __builtin_amdgcn_s_setprio(0);

    bf16x8 pa[2];
#pragma unroll
    for (int c2 = 0; c2 < 2; c2++) {
      float p0f = exp2f(fmaf(s[2 * c2][0], C1, bf2f(bvc[2 * c2].x)));
      float p1f = exp2f(fmaf(s[2 * c2][1], C1, bf2f(bvc[2 * c2].y)));
      float p2f = exp2f(fmaf(s[2 * c2][2], C1, bf2f(bvc[2 * c2].z)));
      float p3f = exp2f(fmaf(s[2 * c2][3], C1, bf2f(bvc[2 * c2].w)));
      float p4f = exp2f(fmaf(s[2 * c2 + 1][0], C1, bf2f(bvc[2 * c2 + 1].x)));
      float p5f = exp2f(fmaf(s[2 * c2 + 1][1], C1, bf2f(bvc[2 * c2 + 1].y)));
      float p6f = exp2f(fmaf(s[2 * c2 + 1][2], C1, bf2f(bvc[2 * c2 + 1].z)));
      float p7f = exp2f(fmaf(s[2 * c2 + 1][3], C1, bf2f(bvc[2 * c2 + 1].w)));
      uint4 W;
      W.x = __builtin_amdgcn_perm(__builtin_bit_cast(unsigned, p1f),
                                  __builtin_bit_cast(unsigned, p0f), 0x07060302u);
      W.y = __builtin_amdgcn_perm(__builtin_bit_cast(unsigned, p3f),
                                  __builtin_bit_cast(unsigned, p2f), 0x07060302u);
      W.z = __builtin_amdgcn_perm(__builtin_bit_cast(unsigned, p5f),
                                  __builtin_bit_cast(unsigned, p4f), 0x07060302u);
      W.w = __builtin_amdgcn_perm(__builtin_bit_cast(unsigned, p7f),
                                  __builtin_bit_cast(unsigned, p6f), 0x07060302u);
      pa[c2] = __builtin_bit_cast(bf16x8, W);
    }

    __builtin_amdgcn_s_setprio(1);
#pragma unroll
    for (int c2 = 0; c2 < 2; c2++) {
      rsacc = __builtin_amdgcn_mfma_f32_16x16x32_bf16(pa[c2], ones, rsacc, 0, 0, 0);
#pragma unroll
      for (int df = 0; df < 4; df++) {
        bf16x8 vf = *reinterpret_cast<const bf16x8*>(
            vt + (df * 16 + lr) * 64 + (((4 * c2 + g) ^ (lr & 7)) << 3));
        acc[df] = __builtin_amdgcn_mfma_f32_16x16x32_bf16(pa[c2], vf, acc[df], 0, 0, 0);
      }
    }
    __builtin_amdgcn_s_setprio(0);

    if (kt < 31) {
      bvc[0] = bvn[0]; bvc[1] = bvn[1]; bvc[2] = bvn[2]; bvc[3] = bvn[3];
    }
    __syncthreads();
  }
  float l0 = 1.0f / rsacc[0], l1 = 1.0f / rsacc[1];
  float l2 = 1.0f / rsacc[2], l3 = 1.0f / rsacc[3];
  unsigned short* op = ctxb + (bS + qbase + 4 * g) * HID + h * HD + lr;
#pragma unroll
  for (int df = 0; df < 4; df++) {
    op[0 * HID + df * 16] = f2bf(acc[df][0] * l0);
    op[1 * HID + df * 16] = f2bf(acc[df][1] * l1);
    op[2 * HID + df * 16] = f2bf(acc[df][2] * l2);
    op[3 * HID + df * 16] = f2bf(acc[df][3] * l3);
  }
}

extern "C" void kernel_launch(void* const* d_in, const int* in_sizes, int n_in,
                              void* d_out, int out_size, void* d_ws, size_t ws_size,
                              hipStream_t stream) {
  const float* x = (const float*)d_in[0];
  const unsigned char* mask = (const unsigned char*)d_in[1];
  const float* Wq = (const float*)d_in[2];
  const float* bq = (const float*)d_in[3];
  const float* Wk = (const float*)d_in[4];
  const float* bk = (const float*)d_in[5];
  const float* Wv = (const float*)d_in[6];
  const float* bv = (const float*)d_in[7];
  const float* Wo = (const float*)d_in[8];
  const float* bo = (const float*)d_in[9];
  float* out = (float*)d_out;

  char* ws = (char*)d_ws;
  const size_t MiB = 1024 * 1024;
  unsigned short* xb  = (unsigned short*)(ws + 0 * MiB);   // 8 MiB
  unsigned short* nxb = (unsigned short*)(ws + 8 * MiB);   // 8 MiB
  unsigned short* Wb  = (unsigned short*)(ws + 16 * MiB);  // 8 MiB
  unsigned short* QK  = (unsigned short*)(ws + 24 * MiB);  // 16 MiB [4096][2048]
  unsigned short* VT  = (unsigned short*)(ws + 40 * MiB);  // 8 MiB  [1024][4096]
  unsigned short* D2  = (unsigned short*)(ws + 48 * MiB);  // 16 MiB bf16 log2-bias
  unsigned short* ctx = (unsigned short*)(ws + 64 * MiB);  // 8 MiB

  // prep: weight conversion (2048 blocks) + rownorm (4096 blocks)
  prep_kernel<<<6144, 256, 0, stream>>>(x, Wq, Wk, Wv, Wo, Wb, xb, nxb);
  // mega GEMM: QK-proj | VT-proj | symmetric sim (one dispatch, 1040 blocks)
  mega_gemm<<<1040, 256, 0, stream>>>(xb, nxb, Wb, QK, VT, D2, bq, bk, bv, mask);
  // flash attention over all heads
  flash_kernel<<<dim3(NH, SEQ / 64, NB), 256, 0, stream>>>(QK, VT, D2, ctx);
  // output projection
  gemm_out<<<dim3(8, 32), 256, 0, stream>>>(
      ctx, Wb + (size_t)3 * HID * HID, out, bo);
}